// Round 6
// baseline (38.093 us; speedup 1.0000x reference)
//
#include <hip/hip_runtime.h>

// IIR filter bank: B=16, T=32768, F=30, order 6 (K=7).
// Overlap-and-discard chunking. One thread per (b,f,chunk).
// R3: cached float4 stores (NT = 3x write amplification; lanes write rows
//     128KB apart, L2 must merge per-lane 16B stores into full lines).
// R4: CHUNK 256->128 (more waves). R5: CHUNK 64, WARM 192.
//     Evidence trend R0->R4: waves 960->1920, dur 51.6->36.4 us, VALUBusy
//     ~25% -> latency-bound, compiler won't hold prefetch regs (VGPR=44).
//     TLP is the lever: 3840 waves = 3.75/SIMD. Truncation 0.95^192~5e-5,
//     contributes <~0.5 abs vs threshold 9.96 (absmax flat at 2.0 so far).

#define BB 16
#define TT 32768
#define FF 30
#define KK 7
#define ORD 6
#define CHUNK 64
#define WARM 192
#define NCHUNK (TT / CHUNK)  // 512

// Transposed direct-form II step: 13 FMAs, no state shifting.
__device__ __forceinline__ float iir_step(float xv, float st[ORD],
                                          const float bc[KK],
                                          const float ac[ORD]) {
    float y = fmaf(bc[0], xv, st[0]);
#pragma unroll
    for (int j = 0; j < ORD - 1; ++j)
        st[j] = fmaf(-ac[j], y, fmaf(bc[j + 1], xv, st[j + 1]));
    st[ORD - 1] = fmaf(-ac[ORD - 1], y, bc[KK - 1] * xv);
    return y;
}

__device__ __forceinline__ void load16(const float* __restrict__ p,
                                       float4 v[4]) {
#pragma unroll
    for (int q = 0; q < 4; ++q)
        v[q] = *reinterpret_cast<const float4*>(p + 4 * q);
}

template <bool STORE>
__device__ __forceinline__ void proc16(const float4 v[4], float st[ORD],
                                       const float bc[KK], const float ac[ORD],
                                       float* __restrict__ op) {
#pragma unroll
    for (int q = 0; q < 4; ++q) {
        float4 y;
        y.x = iir_step(v[q].x, st, bc, ac);
        y.y = iir_step(v[q].y, st, bc, ac);
        y.z = iir_step(v[q].z, st, bc, ac);
        y.w = iir_step(v[q].w, st, bc, ac);
        if (STORE)
            *reinterpret_cast<float4*>(op + 4 * q) = y;  // cached: L2 merges
    }
}

__global__ __launch_bounds__(256) void iir_chunked_kernel(
    const float* __restrict__ x,    // [B][T]
    const float* __restrict__ bs,   // [F][K]
    const float* __restrict__ as_,  // [F][K]
    float* __restrict__ out)        // [B][F][T]
{
    const int tid = blockIdx.x * blockDim.x + threadIdx.x;
    // f fastest: lanes in a wave mostly share (b, chunk) -> broadcast x loads
    const int f = tid % FF;
    const int rest = tid / FF;
    const int chunk = rest % NCHUNK;
    const int b = rest / NCHUNK;

    const float inv_a0 = 1.0f / as_[f * KK];
    float bc[KK], ac[ORD];
#pragma unroll
    for (int j = 0; j < KK; ++j) bc[j] = bs[f * KK + j] * inv_a0;
#pragma unroll
    for (int j = 0; j < ORD; ++j) ac[j] = as_[f * KK + 1 + j] * inv_a0;

    const float* __restrict__ xrow = x + b * TT;
    const int t0 = chunk * CHUNK;
    int ws = t0 - WARM;
    if (ws < 0) ws = 0;  // ws is a multiple of 64 -> 16B-aligned loads

    float st[ORD];
#pragma unroll
    for (int j = 0; j < ORD; ++j) st[j] = 0.0f;

    // Prime the double buffer: A=[ws,ws+16), B=[ws+16,ws+32).
    float4 A[4], B[4];
    load16(xrow + ws, A);
    load16(xrow + ws + 16, B);

    // Warm-up (length 0, 64, 128, or 192 -> multiple of 32... 64 and 192 are
    // multiples of 32; ws>=0 cases: t0-ws in {0,64,128,192}, all /32).
    for (int t = ws; t < t0; t += 32) {
        float4 NA[4], NB[4];
        load16(xrow + t + 32, NA);
        load16(xrow + t + 48, NB);
        proc16<false>(A, st, bc, ac, nullptr);
        proc16<false>(B, st, bc, ac, nullptr);
#pragma unroll
        for (int q = 0; q < 4; ++q) { A[q] = NA[q]; B[q] = NB[q]; }
    }

    // Output phase: 2 iterations of 32 samples.
    float* __restrict__ orow = out + (b * FF + f) * TT;
#pragma unroll
    for (int i = 0; i < CHUNK / 32; ++i) {
        const int t = t0 + 32 * i;
        int pf = t + 32;
        if (pf > TT - 32) pf = TT - 32;  // clamp final prefetch (last chunk)
        float4 NA[4], NB[4];
        load16(xrow + pf, NA);
        load16(xrow + pf + 16, NB);
        proc16<true>(A, st, bc, ac, orow + t);
        proc16<true>(B, st, bc, ac, orow + t + 16);
#pragma unroll
        for (int q = 0; q < 4; ++q) { A[q] = NA[q]; B[q] = NB[q]; }
    }
}

extern "C" void kernel_launch(void* const* d_in, const int* in_sizes, int n_in,
                              void* d_out, int out_size, void* d_ws,
                              size_t ws_size, hipStream_t stream) {
    const float* x   = (const float*)d_in[0];
    const float* bs  = (const float*)d_in[1];
    const float* as_ = (const float*)d_in[2];
    float* out = (float*)d_out;

    const int total = BB * FF * NCHUNK;  // 245760 threads = 3840 waves
    const int block = 256;
    const int grid = total / block;      // 960
    hipLaunchKernelGGL(iir_chunked_kernel, dim3(grid), dim3(block), 0, stream,
                       x, bs, as_, out);
}

// Round 7
// 31.677 us; speedup vs baseline: 1.2025x; 1.2025x over previous
//
#include <hip/hip_runtime.h>

// IIR filter bank: B=16, T=32768, F=30, order 6 (K=7).
// Overlap-and-discard chunking (WARM=192; 0.95^192~5e-5 truncation).
// R6: both memory streams through LDS.
//   Evidence: VALUBusy flat ~21-26% from 1..4 waves/SIMD (R0..R5) -> memory
//   CONTENTION not latency; stores are 64 distinct 16B-partial lines per
//   instruction (lanes' rows 128KB apart); R2's NT test proved the partial-
//   line scatter (3x write amplification without L2 merging).
//   Fix: block = (b, 512-sample span). 240 threads compute 30f x 8 chunks
//   into LDS tile [30][513] (bank f+t: conflict-free), then ALL threads
//   flush with contiguous float4 stores = full 64B lines only.
//   x staged in LDS too (704 floats): compute loop has ZERO global ops.
//   Zero-fill x below t=0 and run warm-up unconditionally (zero input keeps
//   zero state -> exact), so trip counts are compile-time constants.

#define BB 16
#define TT 32768
#define FF 30
#define KK 7
#define ORD 6
#define CHUNK 64
#define WARM 192
#define CPB 8                  // chunks per block
#define TSPAN (CPB * CHUNK)    // 512 samples per block
#define NBC (TT / TSPAN)       // 64 block-columns per row
#define YSTR (TSPAN + 1)       // 513: bank(f,t) = f + t  -> conflict-free
#define XTILE (WARM + TSPAN)   // 704 floats staged x

// Transposed direct-form II step: 13 FMAs, no state shifting.
__device__ __forceinline__ float iir_step(float xv, float st[ORD],
                                          const float bcf[KK],
                                          const float acf[ORD]) {
    float y = fmaf(bcf[0], xv, st[0]);
#pragma unroll
    for (int j = 0; j < ORD - 1; ++j)
        st[j] = fmaf(-acf[j], y, fmaf(bcf[j + 1], xv, st[j + 1]));
    st[ORD - 1] = fmaf(-acf[ORD - 1], y, bcf[KK - 1] * xv);
    return y;
}

__global__ __launch_bounds__(256) void iir_lds_kernel(
    const float* __restrict__ x,    // [B][T]
    const float* __restrict__ bs,   // [F][K]
    const float* __restrict__ as_,  // [F][K]
    float* __restrict__ out)        // [B][F][T]
{
    __shared__ float ly[FF * YSTR];                 // 61560 B output tile
    __shared__ __align__(16) float lx[XTILE];       //  2816 B x tile

    const int tid = threadIdx.x;
    const int b   = blockIdx.x / NBC;
    const int bc  = blockIdx.x % NBC;
    const int bt0 = bc * TSPAN;
    const int xs  = bt0 - WARM;     // may be negative for bc==0

    const float* __restrict__ xrow = x + b * TT;

    // Cooperative x stage: 176 float4 loads (coalesced); zero-fill t<0.
    if (tid < XTILE / 4) {
        const int t = xs + 4 * tid;
        float4 v = make_float4(0.f, 0.f, 0.f, 0.f);
        if (t >= 0) v = *reinterpret_cast<const float4*>(xrow + t);
        *reinterpret_cast<float4*>(lx + 4 * tid) = v;
    }
    __syncthreads();

    if (tid < FF * CPB) {           // 240 compute threads
        const int f  = tid % FF;    // f fastest: x reads broadcast in-wave
        const int cl = tid / FF;    // chunk-in-block 0..7

        const float inv_a0 = 1.0f / as_[f * KK];
        float bcf[KK], acf[ORD];
#pragma unroll
        for (int j = 0; j < KK; ++j) bcf[j] = bs[f * KK + j] * inv_a0;
#pragma unroll
        for (int j = 0; j < ORD; ++j) acf[j] = as_[f * KK + 1 + j] * inv_a0;

        float st[ORD];
#pragma unroll
        for (int j = 0; j < ORD; ++j) st[j] = 0.0f;

        // This chunk's x window in the tile: warm [0,WARM), out [WARM,+CHUNK)
        const float* lxc = lx + cl * CHUNK;

#pragma unroll 8
        for (int s = 0; s < WARM; s += 4) {
            const float4 v = *reinterpret_cast<const float4*>(lxc + s);
            iir_step(v.x, st, bcf, acf);
            iir_step(v.y, st, bcf, acf);
            iir_step(v.z, st, bcf, acf);
            iir_step(v.w, st, bcf, acf);
        }

        float* lyc = ly + f * YSTR + cl * CHUNK;
#pragma unroll 4
        for (int s = 0; s < CHUNK; s += 4) {
            const float4 v = *reinterpret_cast<const float4*>(lxc + WARM + s);
            lyc[s]     = iir_step(v.x, st, bcf, acf);
            lyc[s + 1] = iir_step(v.y, st, bcf, acf);
            lyc[s + 2] = iir_step(v.z, st, bcf, acf);
            lyc[s + 3] = iir_step(v.w, st, bcf, acf);
        }
    }
    __syncthreads();

    // Flush: 30 rows x 512 floats = 3840 float4s, 15 per thread.
    // Lanes write consecutive float4s within a row -> full 64B lines only.
    float* __restrict__ obase = out + b * FF * TT + bt0;
#pragma unroll
    for (int it = 0; it < (FF * TSPAN / 4) / 256; ++it) {  // 15
        const int j  = tid + 256 * it;
        const int f  = j >> 7;            // 128 float4 per row
        const int tl = (j & 127) << 2;
        const float* p = ly + f * YSTR + tl;
        float4 v;
        v.x = p[0]; v.y = p[1]; v.z = p[2]; v.w = p[3];
        *reinterpret_cast<float4*>(obase + f * TT + tl) = v;
    }
}

extern "C" void kernel_launch(void* const* d_in, const int* in_sizes, int n_in,
                              void* d_out, int out_size, void* d_ws,
                              size_t ws_size, hipStream_t stream) {
    const float* x   = (const float*)d_in[0];
    const float* bs  = (const float*)d_in[1];
    const float* as_ = (const float*)d_in[2];
    float* out = (float*)d_out;

    const int grid = BB * NBC;  // 1024 blocks x 256 threads
    hipLaunchKernelGGL(iir_lds_kernel, dim3(grid), dim3(256), 0, stream,
                       x, bs, as_, out);
}

// Round 8
// 30.817 us; speedup vs baseline: 1.2361x; 1.0279x over previous
//
#include <hip/hip_runtime.h>

// IIR filter bank: B=16, T=32768, F=30, order 6 (K=7).
// Overlap-and-discard chunking; both memory streams via LDS (R6 win).
// R7: WARM 192->128 (trunc 1.4e-3 * state~500 ~ 0.7 abs, noise floor is
//     2.0, threshold 9.96) => -25% VALU work. TSPAN 512->256 with
//     128-thread blocks: LDS 32.4KB -> 5 resident blocks/CU (was 2) for
//     compute/flush phase overlap across blocks; 2048 blocks = 8 gens/CU.

#define BB 16
#define TT 32768
#define FF 30
#define KK 7
#define ORD 6
#define CHUNK 64
#define WARM 128
#define CPB 4                  // chunks per block
#define TSPAN (CPB * CHUNK)    // 256 samples per block
#define NBC (TT / TSPAN)       // 128 block-columns per row
#define YSTR (TSPAN + 1)       // 257: bank(f,t) = f + t -> ~2-way max
#define XTILE (WARM + TSPAN)   // 384 floats staged x
#define BLK 128                // threads per block

// Transposed direct-form II step: 13 FMAs, no state shifting.
__device__ __forceinline__ float iir_step(float xv, float st[ORD],
                                          const float bcf[KK],
                                          const float acf[ORD]) {
    float y = fmaf(bcf[0], xv, st[0]);
#pragma unroll
    for (int j = 0; j < ORD - 1; ++j)
        st[j] = fmaf(-acf[j], y, fmaf(bcf[j + 1], xv, st[j + 1]));
    st[ORD - 1] = fmaf(-acf[ORD - 1], y, bcf[KK - 1] * xv);
    return y;
}

__global__ __launch_bounds__(BLK) void iir_lds_kernel(
    const float* __restrict__ x,    // [B][T]
    const float* __restrict__ bs,   // [F][K]
    const float* __restrict__ as_,  // [F][K]
    float* __restrict__ out)        // [B][F][T]
{
    __shared__ float ly[FF * YSTR];             // 30840 B output tile
    __shared__ __align__(16) float lx[XTILE];   //  1536 B x tile

    const int tid = threadIdx.x;
    const int b   = blockIdx.x / NBC;
    const int bc  = blockIdx.x % NBC;
    const int bt0 = bc * TSPAN;
    const int xs  = bt0 - WARM;     // negative only for bc==0

    const float* __restrict__ xrow = x + b * TT;

    // Cooperative x stage: 96 float4 loads; zero-fill t<0 (zero input keeps
    // zero state -> warm-up over the pad is exact for bc==0).
    if (tid < XTILE / 4) {
        const int t = xs + 4 * tid;
        float4 v = make_float4(0.f, 0.f, 0.f, 0.f);
        if (t >= 0) v = *reinterpret_cast<const float4*>(xrow + t);
        *reinterpret_cast<float4*>(lx + 4 * tid) = v;
    }
    __syncthreads();

    if (tid < FF * CPB) {           // 120 compute threads
        const int f  = tid % FF;    // f fastest: x reads broadcast in-wave
        const int cl = tid / FF;    // chunk-in-block 0..3

        const float inv_a0 = 1.0f / as_[f * KK];
        float bcf[KK], acf[ORD];
#pragma unroll
        for (int j = 0; j < KK; ++j) bcf[j] = bs[f * KK + j] * inv_a0;
#pragma unroll
        for (int j = 0; j < ORD; ++j) acf[j] = as_[f * KK + 1 + j] * inv_a0;

        float st[ORD];
#pragma unroll
        for (int j = 0; j < ORD; ++j) st[j] = 0.0f;

        // This chunk's x window: warm [0,WARM), output [WARM, WARM+CHUNK)
        const float* lxc = lx + cl * CHUNK;

#pragma unroll 8
        for (int s = 0; s < WARM; s += 4) {
            const float4 v = *reinterpret_cast<const float4*>(lxc + s);
            iir_step(v.x, st, bcf, acf);
            iir_step(v.y, st, bcf, acf);
            iir_step(v.z, st, bcf, acf);
            iir_step(v.w, st, bcf, acf);
        }

        float* lyc = ly + f * YSTR + cl * CHUNK;
#pragma unroll 4
        for (int s = 0; s < CHUNK; s += 4) {
            const float4 v = *reinterpret_cast<const float4*>(lxc + WARM + s);
            lyc[s]     = iir_step(v.x, st, bcf, acf);
            lyc[s + 1] = iir_step(v.y, st, bcf, acf);
            lyc[s + 2] = iir_step(v.z, st, bcf, acf);
            lyc[s + 3] = iir_step(v.w, st, bcf, acf);
        }
    }
    __syncthreads();

    // Flush: 30 rows x 256 floats = 1920 float4, 15 per thread.
    // One wave covers one full row (64 float4 = 1KB) -> full 64B lines.
    float* __restrict__ obase = out + b * FF * TT + bt0;
#pragma unroll
    for (int it = 0; it < (FF * TSPAN / 4) / BLK; ++it) {  // 15
        const int j  = tid + BLK * it;
        const int f  = j >> 6;            // 64 float4 per row
        const int tl = (j & 63) << 2;
        const float* p = ly + f * YSTR + tl;
        float4 v;
        v.x = p[0]; v.y = p[1]; v.z = p[2]; v.w = p[3];
        *reinterpret_cast<float4*>(obase + f * TT + tl) = v;
    }
}

extern "C" void kernel_launch(void* const* d_in, const int* in_sizes, int n_in,
                              void* d_out, int out_size, void* d_ws,
                              size_t ws_size, hipStream_t stream) {
    const float* x   = (const float*)d_in[0];
    const float* bs  = (const float*)d_in[1];
    const float* as_ = (const float*)d_in[2];
    float* out = (float*)d_out;

    const int grid = BB * NBC;  // 2048 blocks x 128 threads
    hipLaunchKernelGGL(iir_lds_kernel, dim3(grid), dim3(BLK), 0, stream,
                       x, bs, as_, out);
}

// Round 9
// 30.707 us; speedup vs baseline: 1.2405x; 1.0036x over previous
//
#include <hip/hip_runtime.h>

// IIR filter bank: B=16, T=32768, F=30, order 6 (K=7).
// Overlap-and-discard chunking; both memory streams via LDS (R6).
// R7: WARM=128, TSPAN=256, BLK=128 (4-5 resident blocks/CU).
// R8: ALL LDS accesses 16B. YSTR 257->260 (1040B row stride: 16B-aligned,
//     write banks (4f+c)%32 ~4-way). Compute writes ds_write_b128 (was 4x
//     ds_write_b32); flush reads ds_read_b128, one wave = one row of 64
//     consecutive float4 -> sequential, conflict-free. R7's flush did 4
//     scalar reads/float4 with lanes 16B apart = 8 banks = 8-way conflict
//     (~2.94x, m136) -> ~16us of serialized LDS-pipe time. This removes it.

#define BB 16
#define TT 32768
#define FF 30
#define KK 7
#define ORD 6
#define CHUNK 64
#define WARM 128
#define CPB 4                  // chunks per block
#define TSPAN (CPB * CHUNK)    // 256 samples per block
#define NBC (TT / TSPAN)       // 128 block-columns per row
#define YSTR 260               // 16B-aligned row stride, breaks bank align
#define XTILE (WARM + TSPAN)   // 384 floats staged x
#define BLK 128                // threads per block

// Transposed direct-form II step: 13 FMAs, no state shifting.
__device__ __forceinline__ float iir_step(float xv, float st[ORD],
                                          const float bcf[KK],
                                          const float acf[ORD]) {
    float y = fmaf(bcf[0], xv, st[0]);
#pragma unroll
    for (int j = 0; j < ORD - 1; ++j)
        st[j] = fmaf(-acf[j], y, fmaf(bcf[j + 1], xv, st[j + 1]));
    st[ORD - 1] = fmaf(-acf[ORD - 1], y, bcf[KK - 1] * xv);
    return y;
}

__global__ __launch_bounds__(BLK) void iir_lds_kernel(
    const float* __restrict__ x,    // [B][T]
    const float* __restrict__ bs,   // [F][K]
    const float* __restrict__ as_,  // [F][K]
    float* __restrict__ out)        // [B][F][T]
{
    __shared__ __align__(16) float ly[FF * YSTR];   // 31200 B output tile
    __shared__ __align__(16) float lx[XTILE];       //  1536 B x tile

    const int tid = threadIdx.x;
    const int b   = blockIdx.x / NBC;
    const int bc  = blockIdx.x % NBC;
    const int bt0 = bc * TSPAN;
    const int xs  = bt0 - WARM;     // negative only for bc==0

    const float* __restrict__ xrow = x + b * TT;

    // Cooperative x stage: 96 float4 loads; zero-fill t<0 (zero input keeps
    // zero state -> warm-up over the pad is exact for bc==0).
    if (tid < XTILE / 4) {
        const int t = xs + 4 * tid;
        float4 v = make_float4(0.f, 0.f, 0.f, 0.f);
        if (t >= 0) v = *reinterpret_cast<const float4*>(xrow + t);
        *reinterpret_cast<float4*>(lx + 4 * tid) = v;
    }
    __syncthreads();

    if (tid < FF * CPB) {           // 120 compute threads
        const int f  = tid % FF;    // f fastest: x reads broadcast in-wave
        const int cl = tid / FF;    // chunk-in-block 0..3

        const float inv_a0 = 1.0f / as_[f * KK];
        float bcf[KK], acf[ORD];
#pragma unroll
        for (int j = 0; j < KK; ++j) bcf[j] = bs[f * KK + j] * inv_a0;
#pragma unroll
        for (int j = 0; j < ORD; ++j) acf[j] = as_[f * KK + 1 + j] * inv_a0;

        float st[ORD];
#pragma unroll
        for (int j = 0; j < ORD; ++j) st[j] = 0.0f;

        // This chunk's x window: warm [0,WARM), output [WARM, WARM+CHUNK)
        const float* lxc = lx + cl * CHUNK;

#pragma unroll 8
        for (int s = 0; s < WARM; s += 4) {
            const float4 v = *reinterpret_cast<const float4*>(lxc + s);
            iir_step(v.x, st, bcf, acf);
            iir_step(v.y, st, bcf, acf);
            iir_step(v.z, st, bcf, acf);
            iir_step(v.w, st, bcf, acf);
        }

        float* lyc = ly + f * YSTR + cl * CHUNK;   // 16B-aligned
#pragma unroll 4
        for (int s = 0; s < CHUNK; s += 4) {
            const float4 v = *reinterpret_cast<const float4*>(lxc + WARM + s);
            float4 y;
            y.x = iir_step(v.x, st, bcf, acf);
            y.y = iir_step(v.y, st, bcf, acf);
            y.z = iir_step(v.z, st, bcf, acf);
            y.w = iir_step(v.w, st, bcf, acf);
            *reinterpret_cast<float4*>(lyc + s) = y;   // one ds_write_b128
        }
    }
    __syncthreads();

    // Flush: 30 rows x 256 floats = 1920 float4, 15 per thread.
    // Wave w, iter it reads row f = 2*it + w as 64 consecutive float4
    // (sequential ds_read_b128, conflict-free) and writes 1KB contiguous
    // to global (full 64B lines).
    float* __restrict__ obase = out + b * FF * TT + bt0;
#pragma unroll
    for (int it = 0; it < (FF * TSPAN / 4) / BLK; ++it) {  // 15
        const int j  = tid + BLK * it;
        const int f  = j >> 6;            // 64 float4 per row
        const int tl = (j & 63) << 2;
        const float4 v = *reinterpret_cast<const float4*>(ly + f * YSTR + tl);
        *reinterpret_cast<float4*>(obase + f * TT + tl) = v;
    }
}

extern "C" void kernel_launch(void* const* d_in, const int* in_sizes, int n_in,
                              void* d_out, int out_size, void* d_ws,
                              size_t ws_size, hipStream_t stream) {
    const float* x   = (const float*)d_in[0];
    const float* bs  = (const float*)d_in[1];
    const float* as_ = (const float*)d_in[2];
    float* out = (float*)d_out;

    const int grid = BB * NBC;  // 2048 blocks x 128 threads
    hipLaunchKernelGGL(iir_lds_kernel, dim3(grid), dim3(BLK), 0, stream,
                       x, bs, as_, out);
}

// Round 10
// 29.352 us; speedup vs baseline: 1.2978x; 1.0462x over previous
//
#include <hip/hip_runtime.h>

// IIR filter bank: B=16, T=32768, F=30, order 6 (K=7).
// Overlap-and-discard chunking (CHUNK=64, WARM=128; trunc ~1.4e-3*state,
// way under threshold). Both memory streams via LDS (R6 win).
// R9: SINGLE-WAVE blocks for phase diversity. Evidence: R6/R7/R8 all ~31us
//     regardless of LDS layout or resident-block count; VALUBusy pinned
//     ~25% in every profiled config -> blocks' stage/compute/flush phases
//     serialize and co-resident multi-wave blocks phase-lock at barriers.
//     BLK=64 (1 wave), TSPAN=128, LDS 16.9KB -> 9 resident blocks/CU at
//     independent phases; intra-wave s_barrier ~free; stage latency and
//     flush stores of some blocks hide under FMA issue of others.

#define BB 16
#define TT 32768
#define FF 30
#define KK 7
#define ORD 6
#define CHUNK 64
#define WARM 128
#define CPB 2                  // chunks per block
#define TSPAN (CPB * CHUNK)    // 128 samples per block
#define NBC (TT / TSPAN)       // 256 block-columns per row
#define YSTR 132               // 16B-aligned row stride (528 B)
#define XTILE (WARM + TSPAN)   // 256 floats staged x
#define BLK 64                 // ONE wave per block

// Transposed direct-form II step: 13 FMAs, no state shifting.
__device__ __forceinline__ float iir_step(float xv, float st[ORD],
                                          const float bcf[KK],
                                          const float acf[ORD]) {
    float y = fmaf(bcf[0], xv, st[0]);
#pragma unroll
    for (int j = 0; j < ORD - 1; ++j)
        st[j] = fmaf(-acf[j], y, fmaf(bcf[j + 1], xv, st[j + 1]));
    st[ORD - 1] = fmaf(-acf[ORD - 1], y, bcf[KK - 1] * xv);
    return y;
}

__global__ __launch_bounds__(BLK) void iir_lds_kernel(
    const float* __restrict__ x,    // [B][T]
    const float* __restrict__ bs,   // [F][K]
    const float* __restrict__ as_,  // [F][K]
    float* __restrict__ out)        // [B][F][T]
{
    __shared__ __align__(16) float ly[FF * YSTR];   // 15840 B output tile
    __shared__ __align__(16) float lx[XTILE];       //  1024 B x tile

    const int tid = threadIdx.x;
    const int b   = blockIdx.x / NBC;
    const int bc  = blockIdx.x % NBC;
    const int bt0 = bc * TSPAN;
    const int xs  = bt0 - WARM;     // negative only for bc==0

    const float* __restrict__ xrow = x + b * TT;

    // Coefficient loads first (latency overlaps the x stage below).
    const int f  = tid % FF;        // lanes 0-29: cl=0, 30-59: cl=1
    const int cl = tid / FF;        // 60-63 idle in compute
    const bool active = tid < FF * CPB;

    float bcf[KK], acf[ORD];
    {
        const int fc = active ? f : 0;
        const float inv_a0 = 1.0f / as_[fc * KK];
#pragma unroll
        for (int j = 0; j < KK; ++j) bcf[j] = bs[fc * KK + j] * inv_a0;
#pragma unroll
        for (int j = 0; j < ORD; ++j) acf[j] = as_[fc * KK + 1 + j] * inv_a0;
    }

    // Cooperative x stage: 64 float4 loads (one per lane); zero-fill t<0
    // (zero input keeps zero state -> warm-up over the pad is exact).
    {
        const int t = xs + 4 * tid;
        float4 v = make_float4(0.f, 0.f, 0.f, 0.f);
        if (t >= 0) v = *reinterpret_cast<const float4*>(xrow + t);
        *reinterpret_cast<float4*>(lx + 4 * tid) = v;
    }
    __syncthreads();   // single-wave block: cheap

    if (active) {
        float st[ORD];
#pragma unroll
        for (int j = 0; j < ORD; ++j) st[j] = 0.0f;

        // This chunk's x window: warm [0,WARM), output [WARM, WARM+CHUNK).
        // Two cl groups read addrs 256B apart: 2-way bank alias = free.
        const float* lxc = lx + cl * CHUNK;

#pragma unroll 8
        for (int s = 0; s < WARM; s += 4) {
            const float4 v = *reinterpret_cast<const float4*>(lxc + s);
            iir_step(v.x, st, bcf, acf);
            iir_step(v.y, st, bcf, acf);
            iir_step(v.z, st, bcf, acf);
            iir_step(v.w, st, bcf, acf);
        }

        float* lyc = ly + f * YSTR + cl * CHUNK;   // 16B-aligned
#pragma unroll 4
        for (int s = 0; s < CHUNK; s += 4) {
            const float4 v = *reinterpret_cast<const float4*>(lxc + WARM + s);
            float4 y;
            y.x = iir_step(v.x, st, bcf, acf);
            y.y = iir_step(v.y, st, bcf, acf);
            y.z = iir_step(v.z, st, bcf, acf);
            y.w = iir_step(v.w, st, bcf, acf);
            *reinterpret_cast<float4*>(lyc + s) = y;   // one ds_write_b128
        }
    }
    __syncthreads();

    // Flush: 30 rows x 128 floats = 960 float4, 15 per lane. Lanes 0-31
    // cover row 2it, lanes 32-63 row 2it+1: two contiguous 512B runs per
    // instruction -> full 64B lines only.
    float* __restrict__ obase = out + b * FF * TT + bt0;
#pragma unroll
    for (int it = 0; it < (FF * TSPAN / 4) / BLK; ++it) {  // 15
        const int j  = tid + BLK * it;
        const int fr = j >> 5;            // 32 float4 per row
        const int tl = (j & 31) << 2;
        const float4 v = *reinterpret_cast<const float4*>(ly + fr * YSTR + tl);
        *reinterpret_cast<float4*>(obase + fr * TT + tl) = v;
    }
}

extern "C" void kernel_launch(void* const* d_in, const int* in_sizes, int n_in,
                              void* d_out, int out_size, void* d_ws,
                              size_t ws_size, hipStream_t stream) {
    const float* x   = (const float*)d_in[0];
    const float* bs  = (const float*)d_in[1];
    const float* as_ = (const float*)d_in[2];
    float* out = (float*)d_out;

    const int grid = BB * NBC;  // 4096 single-wave blocks
    hipLaunchKernelGGL(iir_lds_kernel, dim3(grid), dim3(BLK), 0, stream,
                       x, bs, as_, out);
}